// Round 3
// baseline (443.971 us; speedup 1.0000x reference)
//
#include <hip/hip_runtime.h>
#include <math.h>

// Problem constants
#define PSTR 40     // LDS fp16 patch row stride: 80 B (16B-aligned, uniform banks)

typedef _Float16 half8 __attribute__((ext_vector_type(8)));
typedef float    f32x4 __attribute__((ext_vector_type(4)));

__device__ __forceinline__ float fast_tanh(float v) {
    float e = __expf(2.f * v);
    return 1.f - 2.f / (e + 1.f);
}
__device__ __forceinline__ float hsig(float v) {
    return fminf(fmaxf(0.2f * v + 0.5f, 0.f), 1.f);
}

// Pack weights: Wcx[tap][n][ci<32] from Wx[tap][ci][n]; Wch[tap][n][ci] from Wh[tap][ci][n]
__global__ void prep_w(const float* __restrict__ Wx, const float* __restrict__ Wh,
                       _Float16* __restrict__ Wcx, _Float16* __restrict__ Wch) {
    const int k = blockIdx.x;      // 0..575 = tap*64 + ci
    const int n = threadIdx.x;     // 0..127
    const int tap = k >> 6, ci = k & 63;
    if (ci < 32) Wcx[(tap * 128 + n) * 32 + ci]        = (_Float16)Wx[(tap * 32 + ci) * 128 + n];
    else         Wch[(tap * 128 + n) * 32 + (ci - 32)] = (_Float16)Wh[(tap * 32 + (ci - 32)) * 128 + n];
}

// One fused timestep per launch, 512-thread blocks (8 waves) for 4 waves/SIMD.
// Wave (chg=w&1, wm=w>>1): 16 px x 64 gate-ch. acc[nt]: px = wm*16 + quad*4 + r,
// ch = nt*32 + chg*16 + l15  (nt = gate, f = chg*16+l15).
// Grid (8,8,8): blockIdx.x = batch -> round-robin keeps a batch's tiles XCD-local.
// c round-trips through csw (fp32) except t==0 where c starts as 0 in registers.
__global__ __launch_bounds__(512, 4)
void lstm_step_k(const float* __restrict__ x, const _Float16* __restrict__ Wcx,
                 const _Float16* __restrict__ Wch, const float* __restrict__ bias,
                 const float* __restrict__ gamma_, const float* __restrict__ beta_,
                 const float* __restrict__ mmean, const float* __restrict__ mvar,
                 const _Float16* __restrict__ hprev, _Float16* __restrict__ hnext,
                 float* __restrict__ csw, float* __restrict__ out, int t)
{
    __shared__ _Float16 xp[100 * PSTR];   // 8 KB: 10x10 halo x 32 x-ch
    __shared__ _Float16 hp[100 * PSTR];   // 8 KB: 10x10 halo x 32 h-ch

    const int tid  = threadIdx.x;         // 0..511
    const int lane = tid & 63;
    const int w    = tid >> 6;            // 0..7
    const int l15  = lane & 15, quad = lane >> 4;
    const int chg  = w & 1, wm = w >> 1;  // ch-half, px-m-tile
    const int b = blockIdx.x, tx = blockIdx.y, ty = blockIdx.z;
    const int px0 = tx * 8, py0 = ty * 8;
    const int tile = ty * 8 + tx;

    // ---- stage x patch (fp32 -> fp16) and h patch (fp16): one item per thread ----
    const float* xt = x + (((size_t)b * 16 + t) * 4096) * 32;
    if (tid < 400) {
        const int pos = tid >> 2, q = tid & 3;
        const int row = pos / 10, col = pos - row * 10;
        const int gy = py0 + row - 1, gx = px0 + col - 1;
        half8 hv = {0, 0, 0, 0, 0, 0, 0, 0};
        if ((unsigned)gy < 64u && (unsigned)gx < 64u) {
            const float* s = xt + ((size_t)(gy * 64 + gx)) * 32 + q * 8;
            const float4 v0 = *(const float4*)s;
            const float4 v1 = *(const float4*)(s + 4);
            hv = (half8){(_Float16)v0.x, (_Float16)v0.y, (_Float16)v0.z, (_Float16)v0.w,
                         (_Float16)v1.x, (_Float16)v1.y, (_Float16)v1.z, (_Float16)v1.w};
        }
        *(half8*)&xp[pos * PSTR + q * 8] = hv;
    }
    if (t > 0 && tid < 400) {
        const _Float16* hb = hprev + (size_t)b * 4096 * 32;
        const int pos = tid >> 2, q = tid & 3;
        const int row = pos / 10, col = pos - row * 10;
        const int gy = py0 + row - 1, gx = px0 + col - 1;
        half8 hv = {0, 0, 0, 0, 0, 0, 0, 0};
        if ((unsigned)gy < 64u && (unsigned)gx < 64u)
            hv = *(const half8*)(hb + ((size_t)(gy * 64 + gx)) * 32 + q * 8);
        *(half8*)&hp[pos * PSTR + q * 8] = hv;
    }

    // ---- constants (overlap with staging latency) ----
    const int f = chg * 16 + l15;
    float bi[4];
    #pragma unroll
    for (int nt = 0; nt < 4; ++nt) bi[nt] = bias[nt * 32 + f];
    const float inv = gamma_[f] * rsqrtf(mvar[f] + 1e-3f);
    const float bnb = beta_[f] - mmean[f] * inv;

    __syncthreads();

    // ---- cell state: issue load early (consumed after MFMA) ----
    float* cp = csw + (((size_t)b * 64 + tile) * 512 + tid) * 4;
    f32x4 c0 = (f32x4){0.f, 0.f, 0.f, 0.f};
    if (t > 0) c0 = *(const f32x4*)cp;

    f32x4 acc[4];
    #pragma unroll
    for (int nt = 0; nt < 4; ++nt)
        acc[nt] = (f32x4){bi[nt], bi[nt], bi[nt], bi[nt]};

    // A-frag row: px = wm*16 + l15 -> patch row = wm*2 + (l15>>3), col = l15&7
    const int pbase = ((wm * 2 + (l15 >> 3)) * 10 + (l15 & 7)) * PSTR + quad * 8;
    const _Float16* wbx = Wcx + (chg * 16 + l15) * 32 + quad * 8;

    // ---- x-conv: 9 taps x 4 gates ----
    #pragma unroll
    for (int tap = 0; tap < 9; ++tap) {
        const int ky = tap / 3, kx = tap - ky * 3;
        const half8 a0 = *(const half8*)&xp[pbase + (ky * 10 + kx) * PSTR];
        #pragma unroll
        for (int nt = 0; nt < 4; ++nt) {
            const half8 bf = *(const half8*)(wbx + tap * 4096 + nt * 1024);
            acc[nt] = __builtin_amdgcn_mfma_f32_16x16x32_f16(a0, bf, acc[nt], 0, 0, 0);
        }
    }
    // ---- h-conv (skipped at t=0: h0 == 0) ----
    if (t > 0) {
        const _Float16* wbh = Wch + (chg * 16 + l15) * 32 + quad * 8;
        #pragma unroll
        for (int tap = 0; tap < 9; ++tap) {
            const int ky = tap / 3, kx = tap - ky * 3;
            const half8 a0 = *(const half8*)&hp[pbase + (ky * 10 + kx) * PSTR];
            #pragma unroll
            for (int nt = 0; nt < 4; ++nt) {
                const half8 bf = *(const half8*)(wbh + tap * 4096 + nt * 1024);
                acc[nt] = __builtin_amdgcn_mfma_f32_16x16x32_f16(a0, bf, acc[nt], 0, 0, 0);
            }
        }
    }

    // ---- LSTM gate math + BN + writes; px = wm*16 + quad*4 + r ----
    _Float16* hq = hnext + (size_t)b * 4096 * 32;
    float* oq = out + (((size_t)b * 16 + t) * 4096) * 32;
    f32x4 cn0;
    #pragma unroll
    for (int r = 0; r < 4; ++r) {
        const int px = wm * 16 + quad * 4 + r;
        const int gy = py0 + (px >> 3), gx = px0 + (px & 7);
        const float gi = acc[0][r];
        const float gf = acc[1][r];
        const float gc = acc[2][r];
        const float go = acc[3][r];
        const float cn = hsig(gf) * c0[r] + hsig(gi) * fast_tanh(gc);
        const float hv = hsig(go) * fast_tanh(cn);
        cn0[r] = cn;
        const size_t pix = ((size_t)(gy * 64 + gx)) * 32 + f;
        hq[pix] = (_Float16)hv;
        oq[pix] = hv * inv + bnb;
    }
    *(f32x4*)cp = cn0;
}

extern "C" void kernel_launch(void* const* d_in, const int* in_sizes, int n_in,
                              void* d_out, int out_size, void* d_ws, size_t ws_size,
                              hipStream_t stream)
{
    const float* x      = (const float*)d_in[0];
    const float* Wx     = (const float*)d_in[1];
    const float* Wh     = (const float*)d_in[2];
    const float* bias   = (const float*)d_in[3];
    const float* gamma_ = (const float*)d_in[4];
    const float* beta_  = (const float*)d_in[5];
    const float* mmean  = (const float*)d_in[6];
    const float* mvar   = (const float*)d_in[7];
    float* out = (float*)d_out;

    // ws: [h0 2MB][h1 2MB][csw 4MB][Wcx 72KB][Wch 72KB]
    char* wsb = (char*)d_ws;
    _Float16* h0  = (_Float16*)(wsb);
    _Float16* h1  = (_Float16*)(wsb + (1 << 21));
    float*    csw = (float*)(wsb + (1 << 22));
    _Float16* Wcx = (_Float16*)(wsb + (1 << 23));
    _Float16* Wch = (_Float16*)(wsb + (1 << 23) + 73728);

    prep_w<<<dim3(576), dim3(128), 0, stream>>>(Wx, Wh, Wcx, Wch);

    // 16 fused-step launches. No memset: t=0 skips h-conv and starts c=0 in registers.
    _Float16* hpr = h0;
    _Float16* hnx = h1;
    for (int t = 0; t < 16; ++t) {
        lstm_step_k<<<dim3(8, 8, 8), 512, 0, stream>>>(
            x, Wcx, Wch, bias, gamma_, beta_, mmean, mvar, hpr, hnx, csw, out, t);
        _Float16* tmp = hpr; hpr = hnx; hnx = tmp;
    }
}

// Round 5
// 347.195 us; speedup vs baseline: 1.2787x; 1.2787x over previous
//
#include <hip/hip_runtime.h>
#include <math.h>

// LDS strides
#define PSTR 40     // fp16 cell stride: 80 B (32 ch used + pad, 16B-aligned)
#define CSTR 33     // f32 cell stride for c LDS (+1 pad)

typedef _Float16 half8 __attribute__((ext_vector_type(8)));
typedef float    f32x4 __attribute__((ext_vector_type(4)));

__device__ __forceinline__ float fast_tanh(float v) {
    float e = __expf(2.f * v);
    return 1.f - 2.f / (e + 1.f);
}
__device__ __forceinline__ float hsig(float v) {
    return fminf(fmaxf(0.2f * v + 0.5f, 0.f), 1.f);
}
__device__ __forceinline__ int div10(int p) { return (p * 205) >> 11; }  // p < 1024

// Pack weights: Wcx[tap][n][ci<32] from Wx[tap][ci][n]; Wch[tap][n][ci] from Wh[tap][ci][n]
__global__ void prep_w(const float* __restrict__ Wx, const float* __restrict__ Wh,
                       _Float16* __restrict__ Wcx, _Float16* __restrict__ Wch) {
    const int k = blockIdx.x;      // 0..575 = tap*64 + ci
    const int n = threadIdx.x;     // 0..127
    const int tap = k >> 6, ci = k & 63;
    if (ci < 32) Wcx[(tap * 128 + n) * 32 + ci]        = (_Float16)Wx[(tap * 32 + ci) * 128 + n];
    else         Wch[(tap * 128 + n) * 32 + (ci - 32)] = (_Float16)Wh[(tap * 32 + (ci - 32)) * 128 + n];
}

// Two fused timesteps per launch (t even, t+1).
// Phase A: 10x10 region (origin py0-1,px0-1) of h_t/c_t from 12x12 staged halo
//          (origin py0-2,px0-2). out_t written on interior 8x8. h_t -> hpB (LDS),
//          c_t -> cB (LDS); out-of-image ring cells masked to 0 (SAME padding).
//          7 m-tiles of 16 px cover the 100 valid cells (112 slots).
// Phase B: 8x8 tile of t+1 from hpB + staged x_{t+1} (10x10). Writes h_{t+1},
//          c_{t+1} (plain [b][y][x][f] layout), out_{t+1}.
// Wave (chg=w&1, mtg=w>>1); phase A mtile = mt*2+mtg (mtg0:{0,2,4,6} mtg1:{1,3,5});
// phase B mtile8 = mtg*2+mtb. D-frag: px = mtile*16+quad*4+r, f = chg*16+l15.
__global__ __launch_bounds__(256, 2)
void lstm_step2(const float* __restrict__ x, const _Float16* __restrict__ Wcx,
                const _Float16* __restrict__ Wch, const float* __restrict__ bias,
                const float* __restrict__ gamma_, const float* __restrict__ beta_,
                const float* __restrict__ mmean, const float* __restrict__ mvar,
                const _Float16* __restrict__ hprev, _Float16* __restrict__ hnext,
                float* __restrict__ csw, float* __restrict__ out, int t)
{
    __shared__ _Float16 xpA[160 * PSTR];   // 12.8 KB: 12x12+slack x-patch (t)
    __shared__ _Float16 hpA[160 * PSTR];   // 12.8 KB: 12x12+slack h-patch (t-1)
    __shared__ _Float16 xpB[100 * PSTR];   //  8.0 KB: 10x10 x-patch (t+1)
    __shared__ _Float16 hpB[112 * PSTR];   //  9.0 KB: 10x10(+pad) h_t
    __shared__ float    cB [112 * CSTR];   // 14.8 KB: 10x10(+pad) c_t

    const int tid  = threadIdx.x;
    const int lane = tid & 63;
    const int w    = tid >> 6;
    const int l15  = lane & 15, quad = lane >> 4;
    const int chg  = w & 1, mtg = w >> 1;
    const int b = blockIdx.x, tx = blockIdx.y, ty = blockIdx.z;
    const int px0 = tx * 8, py0 = ty * 8;

    // ---- stage phase-A patches: 12x12 (+slack rows), origin (py0-2, px0-2) ----
    const float* xtA = x + (((size_t)b * 16 + t) * 4096) * 32;
    for (int i = tid; i < 640; i += 256) {           // 160 cells x 4 chunks
        const int cell = i >> 2, q = i & 3;
        const int row = cell / 12, col = cell - row * 12;
        const int gy = py0 - 2 + row, gx = px0 - 2 + col;
        half8 hv = {0, 0, 0, 0, 0, 0, 0, 0};
        if ((unsigned)gy < 64u && (unsigned)gx < 64u) {
            const float* s = xtA + ((size_t)(gy * 64 + gx)) * 32 + q * 8;
            const float4 v0 = *(const float4*)s;
            const float4 v1 = *(const float4*)(s + 4);
            hv = (half8){(_Float16)v0.x, (_Float16)v0.y, (_Float16)v0.z, (_Float16)v0.w,
                         (_Float16)v1.x, (_Float16)v1.y, (_Float16)v1.z, (_Float16)v1.w};
        }
        *(half8*)&xpA[cell * PSTR + q * 8] = hv;
    }
    if (t > 0) {
        const _Float16* hb = hprev + (size_t)b * 4096 * 32;
        for (int i = tid; i < 640; i += 256) {
            const int cell = i >> 2, q = i & 3;
            const int row = cell / 12, col = cell - row * 12;
            const int gy = py0 - 2 + row, gx = px0 - 2 + col;
            half8 hv = {0, 0, 0, 0, 0, 0, 0, 0};
            if ((unsigned)gy < 64u && (unsigned)gx < 64u)
                hv = *(const half8*)(hb + ((size_t)(gy * 64 + gx)) * 32 + q * 8);
            *(half8*)&hpA[cell * PSTR + q * 8] = hv;
        }
    }
    // ---- stage phase-B x patch: 10x10, origin (py0-1, px0-1), timestep t+1 ----
    const float* xtB = xtA + (size_t)4096 * 32;
    for (int i = tid; i < 400; i += 256) {
        const int cell = i >> 2, q = i & 3;
        const int row = div10(cell), col = cell - row * 10;
        const int gy = py0 - 1 + row, gx = px0 - 1 + col;
        half8 hv = {0, 0, 0, 0, 0, 0, 0, 0};
        if ((unsigned)gy < 64u && (unsigned)gx < 64u) {
            const float* s = xtB + ((size_t)(gy * 64 + gx)) * 32 + q * 8;
            const float4 v0 = *(const float4*)s;
            const float4 v1 = *(const float4*)(s + 4);
            hv = (half8){(_Float16)v0.x, (_Float16)v0.y, (_Float16)v0.z, (_Float16)v0.w,
                         (_Float16)v1.x, (_Float16)v1.y, (_Float16)v1.z, (_Float16)v1.w};
        }
        *(half8*)&xpB[cell * PSTR + q * 8] = hv;
    }

    // ---- constants ----
    const int f = chg * 16 + l15;
    float bi[4];
    #pragma unroll
    for (int nt = 0; nt < 4; ++nt) bi[nt] = bias[nt * 32 + f];
    const float inv = gamma_[f] * rsqrtf(mvar[f] + 1e-3f);
    const float bnb = beta_[f] - mmean[f] * inv;

    // ---- c_{t-1} halo read (plain layout), overlaps staging latency ----
    const float* cb_g = csw + (size_t)b * 4096 * 32;
    f32x4 cprev[4];
    #pragma unroll
    for (int mt = 0; mt < 4; ++mt) {
        cprev[mt] = (f32x4){0.f, 0.f, 0.f, 0.f};
        const int mtile = mt * 2 + mtg;
        if (t > 0 && mtile < 7) {
            #pragma unroll
            for (int r = 0; r < 4; ++r) {
                const int p = mtile * 16 + quad * 4 + r;
                const int orow = div10(p), ocol = p - orow * 10;
                const int gy = py0 - 1 + orow, gx = px0 - 1 + ocol;
                if ((unsigned)gy < 64u && (unsigned)gx < 64u)
                    cprev[mt][r] = cb_g[((size_t)(gy * 64 + gx)) * 32 + f];
            }
        }
    }

    __syncthreads();

    // ---- phase A MFMA: 7 m-tiles over 10x10 region, 12-wide patch ----
    f32x4 acc[4][4];
    #pragma unroll
    for (int mt = 0; mt < 4; ++mt)
        #pragma unroll
        for (int nt = 0; nt < 4; ++nt)
            acc[mt][nt] = (f32x4){bi[nt], bi[nt], bi[nt], bi[nt]};

    int qm[4];
    #pragma unroll
    for (int mt = 0; mt < 4; ++mt) {
        const int p = (mt * 2 + mtg) * 16 + l15;
        qm[mt] = p + 2 * div10(p);          // 12-wide patch cell for A-frag row
    }
    const _Float16* wbx = Wcx + (chg * 16 + l15) * 32 + quad * 8;
    const _Float16* wbh = Wch + (chg * 16 + l15) * 32 + quad * 8;
    const bool m3 = (mtg == 0);             // mtile 7 doesn't exist for mtg=1

    #pragma unroll
    for (int tap = 0; tap < 9; ++tap) {
        const int ky = tap / 3, kx = tap - ky * 3;
        const int toff = (ky * 12 + kx) * PSTR + quad * 8;
        half8 ax[4];
        #pragma unroll
        for (int mt = 0; mt < 3; ++mt) ax[mt] = *(const half8*)&xpA[qm[mt] * PSTR + toff];
        ax[3] = m3 ? *(const half8*)&xpA[qm[3] * PSTR + toff] : (half8){0,0,0,0,0,0,0,0};
        #pragma unroll
        for (int nt = 0; nt < 4; ++nt) {
            const half8 bf = *(const half8*)(wbx + tap * 4096 + nt * 1024);
            #pragma unroll
            for (int mt = 0; mt < 4; ++mt)
                acc[mt][nt] = __builtin_amdgcn_mfma_f32_16x16x32_f16(ax[mt], bf, acc[mt][nt], 0, 0, 0);
        }
    }
    if (t > 0) {
        #pragma unroll
        for (int tap = 0; tap < 9; ++tap) {
            const int ky = tap / 3, kx = tap - ky * 3;
            const int toff = (ky * 12 + kx) * PSTR + quad * 8;
            half8 ah[4];
            #pragma unroll
            for (int mt = 0; mt < 3; ++mt) ah[mt] = *(const half8*)&hpA[qm[mt] * PSTR + toff];
            ah[3] = m3 ? *(const half8*)&hpA[qm[3] * PSTR + toff] : (half8){0,0,0,0,0,0,0,0};
            #pragma unroll
            for (int nt = 0; nt < 4; ++nt) {
                const half8 bf = *(const half8*)(wbh + tap * 4096 + nt * 1024);
                #pragma unroll
                for (int mt = 0; mt < 4; ++mt)
                    acc[mt][nt] = __builtin_amdgcn_mfma_f32_16x16x32_f16(ah[mt], bf, acc[mt][nt], 0, 0, 0);
            }
        }
    }

    // ---- phase A epilogue: LSTM, park h_t/c_t in LDS (zero outside image),
    //      write out_t on interior 8x8 ----
    float* oqA = out + (((size_t)b * 16 + t) * 4096) * 32;
    #pragma unroll
    for (int mt = 0; mt < 4; ++mt) {
        const int mtile = mt * 2 + mtg;
        if (mtile < 7) {
            #pragma unroll
            for (int r = 0; r < 4; ++r) {
                const int p = mtile * 16 + quad * 4 + r;
                const int orow = div10(p), ocol = p - orow * 10;
                const int gy = py0 - 1 + orow, gx = px0 - 1 + ocol;
                const bool inimg = ((unsigned)gy < 64u) && ((unsigned)gx < 64u);
                const float gi = acc[mt][0][r];
                const float gf = acc[mt][1][r];
                const float gc = acc[mt][2][r];
                const float go = acc[mt][3][r];
                float cn = hsig(gf) * cprev[mt][r] + hsig(gi) * fast_tanh(gc);
                float hv = hsig(go) * fast_tanh(cn);
                if (!inimg) { cn = 0.f; hv = 0.f; }   // SAME-padding semantics
                hpB[p * PSTR + f] = (_Float16)hv;
                cB [p * CSTR + f] = cn;
                if ((unsigned)(orow - 1) < 8u && (unsigned)(ocol - 1) < 8u)
                    oqA[((size_t)(gy * 64 + gx)) * 32 + f] = hv * inv + bnb;
            }
        }
    }

    __syncthreads();

    // ---- phase B MFMA: 4 m-tiles over 8x8 tile, 10-wide patches ----
    f32x4 accB[2][4];
    #pragma unroll
    for (int mtb = 0; mtb < 2; ++mtb)
        #pragma unroll
        for (int nt = 0; nt < 4; ++nt)
            accB[mtb][nt] = (f32x4){bi[nt], bi[nt], bi[nt], bi[nt]};

    int q8[2];
    #pragma unroll
    for (int mtb = 0; mtb < 2; ++mtb) {
        const int p8 = (mtg * 2 + mtb) * 16 + l15;
        q8[mtb] = p8 + 2 * (p8 >> 3);
    }
    #pragma unroll
    for (int tap = 0; tap < 9; ++tap) {
        const int ky = tap / 3, kx = tap - ky * 3;
        const int toff = (ky * 10 + kx) * PSTR + quad * 8;
        const half8 ax0 = *(const half8*)&xpB[q8[0] * PSTR + toff];
        const half8 ax1 = *(const half8*)&xpB[q8[1] * PSTR + toff];
        const half8 ah0 = *(const half8*)&hpB[q8[0] * PSTR + toff];
        const half8 ah1 = *(const half8*)&hpB[q8[1] * PSTR + toff];
        #pragma unroll
        for (int nt = 0; nt < 4; ++nt) {
            const half8 bfx = *(const half8*)(wbx + tap * 4096 + nt * 1024);
            const half8 bfh = *(const half8*)(wbh + tap * 4096 + nt * 1024);
            accB[0][nt] = __builtin_amdgcn_mfma_f32_16x16x32_f16(ax0, bfx, accB[0][nt], 0, 0, 0);
            accB[1][nt] = __builtin_amdgcn_mfma_f32_16x16x32_f16(ax1, bfx, accB[1][nt], 0, 0, 0);
            accB[0][nt] = __builtin_amdgcn_mfma_f32_16x16x32_f16(ah0, bfh, accB[0][nt], 0, 0, 0);
            accB[1][nt] = __builtin_amdgcn_mfma_f32_16x16x32_f16(ah1, bfh, accB[1][nt], 0, 0, 0);
        }
    }

    // ---- phase B epilogue: LSTM with c_t from LDS, write h_{t+1}, c_{t+1}, out_{t+1} ----
    _Float16* hq = hnext + (size_t)b * 4096 * 32;
    float* cq = csw + (size_t)b * 4096 * 32;
    float* oqB = out + (((size_t)b * 16 + t + 1) * 4096) * 32;
    #pragma unroll
    for (int mtb = 0; mtb < 2; ++mtb) {
        #pragma unroll
        for (int r = 0; r < 4; ++r) {
            const int p8 = (mtg * 2 + mtb) * 16 + quad * 4 + r;
            const int orow8 = p8 >> 3, ocol8 = p8 & 7;
            const float ct = cB[(p8 + 2 * orow8 + 11) * CSTR + f];
            const float gi = accB[mtb][0][r];
            const float gf = accB[mtb][1][r];
            const float gc = accB[mtb][2][r];
            const float go = accB[mtb][3][r];
            const float cn = hsig(gf) * ct + hsig(gi) * fast_tanh(gc);
            const float hv = hsig(go) * fast_tanh(cn);
            const int gy = py0 + orow8, gx = px0 + ocol8;
            const size_t pix = ((size_t)(gy * 64 + gx)) * 32 + f;
            hq[pix] = (_Float16)hv;
            cq[pix] = cn;
            oqB[pix] = hv * inv + bnb;
        }
    }
}

extern "C" void kernel_launch(void* const* d_in, const int* in_sizes, int n_in,
                              void* d_out, int out_size, void* d_ws, size_t ws_size,
                              hipStream_t stream)
{
    const float* x      = (const float*)d_in[0];
    const float* Wx     = (const float*)d_in[1];
    const float* Wh     = (const float*)d_in[2];
    const float* bias   = (const float*)d_in[3];
    const float* gamma_ = (const float*)d_in[4];
    const float* beta_  = (const float*)d_in[5];
    const float* mmean  = (const float*)d_in[6];
    const float* mvar   = (const float*)d_in[7];
    float* out = (float*)d_out;

    // ws: [h0 2MB][h1 2MB][csw 4MB plain][Wcx 72KB][Wch 72KB]
    char* wsb = (char*)d_ws;
    _Float16* h0  = (_Float16*)(wsb);
    _Float16* h1  = (_Float16*)(wsb + (1 << 21));
    float*    csw = (float*)(wsb + (1 << 22));
    _Float16* Wcx = (_Float16*)(wsb + (1 << 23));
    _Float16* Wch = (_Float16*)(wsb + (1 << 23) + 73728);

    prep_w<<<dim3(576), dim3(128), 0, stream>>>(Wx, Wh, Wcx, Wch);

    // 8 two-step launches. No memset: t=0 skips h-conv and c-read.
    _Float16* hpr = h0;
    _Float16* hnx = h1;
    for (int tp = 0; tp < 8; ++tp) {
        lstm_step2<<<dim3(8, 8, 8), 256, 0, stream>>>(
            x, Wcx, Wch, bias, gamma_, beta_, mmean, mvar, hpr, hnx, csw, out, 2 * tp);
        _Float16* tmp = hpr; hpr = hnx; hnx = tmp;
    }
}